// Round 5
// baseline (13.995 us; speedup 1.0000x reference)
//
#include <hip/hip_runtime.h>
#include <math.h>

#define THREADS 256
#define W_DIM 2048
#define INV_SQRT8 0.35355339059327373f

// Paired-position fused kernel: thread handles pos and pos+npos/2, which share
// the same w (npos/2 = 64*2048) -> all w-dependent trig/constants computed once.
//   LN1 closed form: r = rsqrt(xs^2 A + xs twoB + Cc), tt = xs*r
//   v[d] = tt*a[d] + r*bb[d] + P[d],  P = [pB(w) | Bf(f)]
//   mu  = tt*sa8 + r*sb8 + pBsum8 + F4
//   s2/8= tt(tt*caa8 + r*cab8 + e1) + r(r*cbb8 + e2) + e3
//   l   = r2*(dt - mu*swlg) + cK ;  pp = masked?0:exp(l); cf = pp*r2
//   q[d]= invS*av[d] - invS*smu ;  out[p] = c2[p] + sum_d M2[p][d] q[d]
//   (M2 = (P O Wv) * ln_g folded at precompute)
__global__ __launch_bounds__(THREADS) void misstsm_fused(
    const float* __restrict__ x, const int* __restrict__ m,
    const float* __restrict__ emb_w, const float* __restrict__ emb_b,
    const float* __restrict__ emb_ln_g, const float* __restrict__ emb_ln_b,
    const float* __restrict__ ln_g, const float* __restrict__ ln_b,
    const float* __restrict__ var_query,
    const float* __restrict__ in_proj_w, const float* __restrict__ in_proj_b,
    const float* __restrict__ out_proj_w, const float* __restrict__ out_proj_b,
    const float* __restrict__ proj_w, const float* __restrict__ proj_b,
    float* __restrict__ out, int npos)
{
    __shared__ float s_M2[64];     // (P O Wv)[p][d] * ln_g[d]
    __shared__ float s_c2[8];
    __shared__ float s_a[8], s_bb[8], s_wlg[8];
    __shared__ float s_F[8][9];    // per-f: Bf[4], Bfsum8, F5, F6, F7, Bfdot
    __shared__ float s_sc[12];     // A,twoB,Cc, swlg,cK, sa8,sb8, caa8,cbb8,cab8, ca,cb

    const int t = threadIdx.x;
    const int half = npos >> 1;
    const int pos = blockIdx.x * THREADS + t;
    const int lp  = (pos < half) ? pos : (half - 1);   // clamped load idx

    // ---- prefetch BOTH positions' data first (hides latency under precompute) ----
    const float4* xv4 = reinterpret_cast<const float4*>(x);
    const int4*   mv4 = reinterpret_cast<const int4*>(m);
    const float4 xa0 = xv4[lp*2+0],        xb0 = xv4[lp*2+1];
    const float4 xa1 = xv4[(lp+half)*2+0], xb1 = xv4[(lp+half)*2+1];
    const int4   ma0 = mv4[lp*2+0],        mb0 = mv4[lp*2+1];
    const int4   ma1 = mv4[(lp+half)*2+0], mb1 = mv4[(lp+half)*2+1];

    // ---- per-block precompute, balanced across 4 waves, ONE sync ----
    if (t < 64) {
        // wave0: M2[p][d] = (P O Wv)[p][d] * ln_g[d]
        const int p = t >> 3, d = t & 7;
        float acc = 0.0f;
        #pragma unroll
        for (int e = 0; e < 8; ++e) {
            float po = 0.0f;
            #pragma unroll
            for (int o = 0; o < 8; ++o) po = fmaf(proj_w[p*8+o], out_proj_w[o*8+e], po);
            acc = fmaf(po, in_proj_w[(16+e)*8 + d], acc);
        }
        s_M2[t] = acc * ln_g[d];
    } else if (t < 72) {
        // wave1a: wlg[d]
        const int d = t - 64;
        float wk = 0.0f;
        #pragma unroll
        for (int e = 0; e < 8; ++e) {
            float qe = in_proj_b[e];
            #pragma unroll
            for (int dd = 0; dd < 8; ++dd) qe = fmaf(in_proj_w[e*8+dd], var_query[dd], qe);
            wk = fmaf(in_proj_w[(8+e)*8 + d], qe, wk);
        }
        s_wlg[d] = ln_g[d] * wk * INV_SQRT8;
    } else if (t < 80) {
        // wave1b: a[d], bb[d]
        const int d = t - 72;
        float ewm = 0.0f, ebm = 0.0f;
        #pragma unroll
        for (int dd = 0; dd < 8; ++dd) { ewm += emb_w[dd]; ebm += emb_b[dd]; }
        ewm *= 0.125f; ebm *= 0.125f;
        s_a[d]  = (emb_w[d] - ewm) * emb_ln_g[d];
        s_bb[d] = (emb_b[d] - ebm) * emb_ln_g[d];
    } else if (t == 80) {
        // wave1c: LN1 quadratic constants
        float ewm = 0.0f, ebm = 0.0f;
        #pragma unroll
        for (int d = 0; d < 8; ++d) { ewm += emb_w[d]; ebm += emb_b[d]; }
        ewm *= 0.125f; ebm *= 0.125f;
        float A = 0.0f, Bc = 0.0f, Cc = 0.0f;
        #pragma unroll
        for (int d = 0; d < 8; ++d) {
            const float dw = emb_w[d] - ewm, db = emb_b[d] - ebm;
            A = fmaf(dw, dw, A); Bc = fmaf(dw, db, Bc); Cc = fmaf(db, db, Cc);
        }
        s_sc[0] = A * 0.125f;
        s_sc[1] = 2.0f * Bc * 0.125f;
        s_sc[2] = Cc * 0.125f + 1e-5f;
    } else if (t >= 128 && t < 136) {
        // wave2a: c2[p]
        const int p = t - 128;
        float c = proj_b[p];
        #pragma unroll
        for (int o = 0; o < 8; ++o) {
            float ob2 = out_proj_b[o];
            #pragma unroll
            for (int e = 0; e < 8; ++e) ob2 = fmaf(out_proj_w[o*8+e], in_proj_b[16+e], ob2);
            c = fmaf(proj_w[p*8+o], ob2, c);
        }
        #pragma unroll
        for (int e = 0; e < 8; ++e) {
            float po = 0.0f;
            #pragma unroll
            for (int o = 0; o < 8; ++o) po = fmaf(proj_w[p*8+o], out_proj_w[o*8+e], po);
            #pragma unroll
            for (int d = 0; d < 8; ++d)
                c = fmaf(po * in_proj_w[(16+e)*8 + d], ln_b[d], c);
        }
        s_c2[p] = c;
    } else if (t == 136) {
        // wave2b: dot-product scalars
        float qv[8]; float bkq = 0.0f;
        #pragma unroll
        for (int e = 0; e < 8; ++e) {
            float qe = in_proj_b[e];
            #pragma unroll
            for (int dd = 0; dd < 8; ++dd) qe = fmaf(in_proj_w[e*8+dd], var_query[dd], qe);
            qv[e] = qe;
            bkq = fmaf(in_proj_b[8+e], qe, bkq);
        }
        float ewm = 0.0f, ebm = 0.0f;
        #pragma unroll
        for (int d = 0; d < 8; ++d) { ewm += emb_w[d]; ebm += emb_b[d]; }
        ewm *= 0.125f; ebm *= 0.125f;
        float sa = 0, sb = 0, caa = 0, cbb = 0, cab = 0, ca = 0, cb = 0, sw = 0, ck = 0;
        #pragma unroll
        for (int d = 0; d < 8; ++d) {
            const float ad = (emb_w[d] - ewm) * emb_ln_g[d];
            const float bd = (emb_b[d] - ebm) * emb_ln_g[d];
            float wk = 0.0f;
            #pragma unroll
            for (int e = 0; e < 8; ++e) wk = fmaf(in_proj_w[(8+e)*8 + d], qv[e], wk);
            const float wl = ln_g[d] * wk * INV_SQRT8;
            sa += ad; sb += bd;
            caa = fmaf(ad, ad, caa); cbb = fmaf(bd, bd, cbb); cab = fmaf(ad, bd, cab);
            ca  = fmaf(ad, wl, ca);  cb  = fmaf(bd, wl, cb);
            sw += wl;
            ck  = fmaf(ln_b[d], wk, ck);
        }
        s_sc[3]  = sw;
        s_sc[4]  = (ck + bkq) * INV_SQRT8;
        s_sc[5]  = sa * 0.125f;
        s_sc[6]  = sb * 0.125f;
        s_sc[7]  = caa * 0.125f;
        s_sc[8]  = cbb * 0.125f;
        s_sc[9]  = cab * 0.25f;
        s_sc[10] = ca;
        s_sc[11] = cb;
    } else if (t >= 192 && t < 200) {
        // wave3: per-f table
        const int f = t - 192;
        const float ff = (float)f;
        float sy0, cy0, sy1, cy1;
        sincosf(ff, &sy0, &cy0);
        sincosf(0.01f * ff, &sy1, &cy1);
        float Bf[4];
        Bf[0] = emb_ln_b[4] + sy0; Bf[1] = emb_ln_b[5] + cy0;
        Bf[2] = emb_ln_b[6] + sy1; Bf[3] = emb_ln_b[7] + cy1;
        float ewm = 0.0f, ebm = 0.0f;
        #pragma unroll
        for (int d = 0; d < 8; ++d) { ewm += emb_w[d]; ebm += emb_b[d]; }
        ewm *= 0.125f; ebm *= 0.125f;
        float qv[8];
        #pragma unroll
        for (int e = 0; e < 8; ++e) {
            float qe = in_proj_b[e];
            #pragma unroll
            for (int dd = 0; dd < 8; ++dd) qe = fmaf(in_proj_w[e*8+dd], var_query[dd], qe);
            qv[e] = qe;
        }
        float bsum = 0, aB = 0, bB = 0, b2 = 0, bdot = 0;
        #pragma unroll
        for (int j = 0; j < 4; ++j) {
            const int d = 4 + j;
            const float ad = (emb_w[d] - ewm) * emb_ln_g[d];
            const float bd = (emb_b[d] - ebm) * emb_ln_g[d];
            float wk = 0.0f;
            #pragma unroll
            for (int e = 0; e < 8; ++e) wk = fmaf(in_proj_w[(8+e)*8 + d], qv[e], wk);
            const float wl = ln_g[d] * wk * INV_SQRT8;
            bsum += Bf[j];
            aB   = fmaf(ad, Bf[j], aB);
            bB   = fmaf(bd, Bf[j], bB);
            b2   = fmaf(Bf[j], Bf[j], b2);
            bdot = fmaf(wl, Bf[j], bdot);
            s_F[f][j] = Bf[j];
        }
        s_F[f][4] = bsum * 0.125f;
        s_F[f][5] = aB * 0.25f;
        s_F[f][6] = bB * 0.25f;
        s_F[f][7] = b2 * 0.125f;
        s_F[f][8] = bdot;
    }
    __syncthreads();

    if (pos >= half) return;
    const int w = pos & (W_DIM - 1);

    const float A    = s_sc[0], twoB = s_sc[1], Cc  = s_sc[2];
    const float swlg = s_sc[3], cK   = s_sc[4];
    const float sa8  = s_sc[5], sb8  = s_sc[6];
    const float caa8 = s_sc[7], cbb8 = s_sc[8], cab8 = s_sc[9];
    const float ca   = s_sc[10], cb  = s_sc[11];

    // ---- w-dependent constants: computed ONCE, shared by both positions ----
    const float fw = (float)w;
    float s1, c1, sl, clo;
    sincosf(fw, &s1, &c1);
    sincosf(0.01f * fw, &sl, &clo);
    float pB[4];
    pB[0] = emb_ln_b[0] + s1;  pB[1] = emb_ln_b[1] + c1;
    pB[2] = emb_ln_b[2] + sl;  pB[3] = emb_ln_b[3] + clo;

    float pBsum = 0, apB = 0, bpB = 0, pB2 = 0, pBdot = 0;
    #pragma unroll
    for (int j = 0; j < 4; ++j) {
        pBsum += pB[j];
        apB   = fmaf(s_a[j],   pB[j], apB);
        bpB   = fmaf(s_bb[j],  pB[j], bpB);
        pB2   = fmaf(pB[j],    pB[j], pB2);
        pBdot = fmaf(s_wlg[j], pB[j], pBdot);
    }
    const float pBsum8  = pBsum * 0.125f;
    const float twoapB8 = apB * 0.25f;
    const float twobpB8 = bpB * 0.25f;
    const float pB28eps = fmaf(pB2, 0.125f, 1e-5f);

    float4* ov4 = reinterpret_cast<float4*>(out);

    auto process = [&](const float4& Xa, const float4& Xb,
                       const int4& Ma, const int4& Mb, int opos) {
        const float xf[8] = {Xa.x, Xa.y, Xa.z, Xa.w, Xb.x, Xb.y, Xb.z, Xb.w};
        const int mk = (Ma.x!=0?1:0) | (Ma.y!=0?2:0) | (Ma.z!=0?4:0) | (Ma.w!=0?8:0)
                     | (Mb.x!=0?16:0) | (Mb.y!=0?32:0) | (Mb.z!=0?64:0) | (Mb.w!=0?128:0);

        float S = 0, SC = 0, ctt = 0, crr = 0, smu = 0;
        float avB[4] = {0, 0, 0, 0};

        #pragma unroll
        for (int f = 0; f < 8; ++f) {
            const float F0 = s_F[f][0], F1 = s_F[f][1], F2 = s_F[f][2], F3 = s_F[f][3];
            const float F4 = s_F[f][4], F5 = s_F[f][5], F6 = s_F[f][6], F7 = s_F[f][7];
            const float F8 = s_F[f][8];
            const float xs = xf[f];
            const float r  = rsqrtf(fmaf(xs, fmaf(xs, A, twoB), Cc));
            const float tt = xs * r;
            const float mu = fmaf(tt, sa8, fmaf(r, sb8, pBsum8 + F4));
            const float s2v = fmaf(tt, fmaf(tt, caa8, fmaf(r, cab8, twoapB8 + F5)),
                                   fmaf(r, fmaf(r, cbb8, twobpB8 + F6), pB28eps + F7));
            const float var = fmaf(-mu, mu, s2v);
            const float r2  = rsqrtf(var);
            const float dt  = fmaf(tt, ca, fmaf(r, cb, pBdot + F8));
            const float l   = fmaf(r2, fmaf(-mu, swlg, dt), cK);
            const float e   = __expf(l);
            const float pp  = ((mk >> f) & 1) ? 0.0f : e;
            const float cf  = pp * r2;
            S += pp; SC += cf;
            ctt = fmaf(cf, tt, ctt);
            crr = fmaf(cf, r,  crr);
            smu = fmaf(cf, mu, smu);
            avB[0] = fmaf(cf, F0, avB[0]);
            avB[1] = fmaf(cf, F1, avB[1]);
            avB[2] = fmaf(cf, F2, avB[2]);
            avB[3] = fmaf(cf, F3, avB[3]);
        }

        const float invS = 1.0f / S;
        const float nism = -invS * smu;
        float q[8];
        #pragma unroll
        for (int j = 0; j < 4; ++j) {
            const float av = fmaf(ctt, s_a[j], fmaf(crr, s_bb[j], SC * pB[j]));
            q[j] = fmaf(invS, av, nism);
        }
        #pragma unroll
        for (int j = 0; j < 4; ++j) {
            const float av = fmaf(ctt, s_a[4+j], fmaf(crr, s_bb[4+j], avB[j]));
            q[4+j] = fmaf(invS, av, nism);
        }

        float o[8];
        #pragma unroll
        for (int p = 0; p < 8; ++p) {
            float dp = s_c2[p];
            #pragma unroll
            for (int d = 0; d < 8; ++d) dp = fmaf(s_M2[p*8+d], q[d], dp);
            o[p] = dp;
        }
        ov4[opos*2+0] = make_float4(o[0], o[1], o[2], o[3]);
        ov4[opos*2+1] = make_float4(o[4], o[5], o[6], o[7]);
    };

    process(xa0, xb0, ma0, mb0, pos);
    process(xa1, xb1, ma1, mb1, pos + half);
}

extern "C" void kernel_launch(void* const* d_in, const int* in_sizes, int n_in,
                              void* d_out, int out_size, void* d_ws, size_t ws_size,
                              hipStream_t stream) {
    const float* x          = (const float*)d_in[0];
    const int*   m          = (const int*)d_in[1];
    const float* emb_w      = (const float*)d_in[2];
    const float* emb_b      = (const float*)d_in[3];
    const float* emb_ln_g   = (const float*)d_in[4];
    const float* emb_ln_b   = (const float*)d_in[5];
    const float* ln_g       = (const float*)d_in[6];
    const float* ln_b       = (const float*)d_in[7];
    const float* var_query  = (const float*)d_in[8];
    const float* in_proj_w  = (const float*)d_in[9];
    const float* in_proj_b  = (const float*)d_in[10];
    const float* out_proj_w = (const float*)d_in[11];
    const float* out_proj_b = (const float*)d_in[12];
    const float* proj_w     = (const float*)d_in[13];
    const float* proj_b     = (const float*)d_in[14];
    float* out = (float*)d_out;

    const int npos = in_sizes[0] / 8;                    // 262144
    const int half = npos >> 1;                          // 131072
    const int grid = (half + THREADS - 1) / THREADS;     // 512
    misstsm_fused<<<grid, THREADS, 0, stream>>>(
        x, m, emb_w, emb_b, emb_ln_g, emb_ln_b, ln_g, ln_b, var_query,
        in_proj_w, in_proj_b, out_proj_w, out_proj_b, proj_w, proj_b,
        out, npos);
}

// Round 6
// 13.673 us; speedup vs baseline: 1.0236x; 1.0236x over previous
//
#include <hip/hip_runtime.h>
#include <math.h>

#define THREADS 256
#define W_DIM 2048
#define INV_SQRT8 0.35355339059327373f
#define LOG2E 1.4426950408889634f

// R4 structure (1 pos/thread) + exp2-folded logit constants + smu
// reconstructed post-loop + direct per-f mask selects.
//   LN1 closed form: r = rsqrt(xs^2 A + xs twoB + Cc), tt = xs*r
//   mu  = tt*sa8 + r*sb8 + pBsum8 + F4
//   s2/8= tt(tt*caa8 + r*cab8 + e1) + r(r*cbb8 + e2) + e3
//   l2  = r2*(dt - mu*swlg) + cK          (pre-scaled by log2e)
//   pp  = masked ? 0 : exp2(l2); cf = pp*r2
//   smu = sa8*ctt + sb8*crr + pBsum8*SC + 0.125*sum(avB)
//   out[p] = c2[p] + sum_d M2[p][d] q[d],  q = invS*av - invS*smu
__global__ __launch_bounds__(THREADS) void misstsm_fused(
    const float* __restrict__ x, const int* __restrict__ m,
    const float* __restrict__ emb_w, const float* __restrict__ emb_b,
    const float* __restrict__ emb_ln_g, const float* __restrict__ emb_ln_b,
    const float* __restrict__ ln_g, const float* __restrict__ ln_b,
    const float* __restrict__ var_query,
    const float* __restrict__ in_proj_w, const float* __restrict__ in_proj_b,
    const float* __restrict__ out_proj_w, const float* __restrict__ out_proj_b,
    const float* __restrict__ proj_w, const float* __restrict__ proj_b,
    float* __restrict__ out, int npos)
{
    __shared__ float s_M2[64];     // (P O Wv)[p][d] * ln_g[d]
    __shared__ float s_c2[8];
    __shared__ float s_a[8], s_bb[8], s_wlg[8];
    __shared__ float s_F[8][9];    // per-f: Bf[4], Bfsum8, F5, F6, F7, Bfdot*log2e
    __shared__ float s_sc[12];     // A,twoB,Cc, swlg',cK', sa8,sb8, caa8,cbb8,cab8, ca',cb'

    const int t = threadIdx.x;
    const int pos = blockIdx.x * THREADS + t;   // grid exact: npos = grid*256

    // ---- prefetch this thread's data FIRST ----
    const float4* xv4 = reinterpret_cast<const float4*>(x);
    const int4*   mv4 = reinterpret_cast<const int4*>(m);
    const float4 xa = xv4[pos*2+0];
    const float4 xb = xv4[pos*2+1];
    const int4   ma = mv4[pos*2+0];
    const int4   mb = mv4[pos*2+1];

    // ---- per-block precompute, balanced across 4 waves, ONE sync ----
    if (t < 64) {
        // wave0: M2[p][d] = (P O Wv)[p][d] * ln_g[d]
        const int p = t >> 3, d = t & 7;
        float acc = 0.0f;
        #pragma unroll
        for (int e = 0; e < 8; ++e) {
            float po = 0.0f;
            #pragma unroll
            for (int o = 0; o < 8; ++o) po = fmaf(proj_w[p*8+o], out_proj_w[o*8+e], po);
            acc = fmaf(po, in_proj_w[(16+e)*8 + d], acc);
        }
        s_M2[t] = acc * ln_g[d];
    } else if (t < 72) {
        // wave1a: wlg[d]  (logit-path: scaled by log2e)
        const int d = t - 64;
        float wk = 0.0f;
        #pragma unroll
        for (int e = 0; e < 8; ++e) {
            float qe = in_proj_b[e];
            #pragma unroll
            for (int dd = 0; dd < 8; ++dd) qe = fmaf(in_proj_w[e*8+dd], var_query[dd], qe);
            wk = fmaf(in_proj_w[(8+e)*8 + d], qe, wk);
        }
        s_wlg[d] = ln_g[d] * wk * (INV_SQRT8 * LOG2E);
    } else if (t < 80) {
        // wave1b: a[d], bb[d]
        const int d = t - 72;
        float ewm = 0.0f, ebm = 0.0f;
        #pragma unroll
        for (int dd = 0; dd < 8; ++dd) { ewm += emb_w[dd]; ebm += emb_b[dd]; }
        ewm *= 0.125f; ebm *= 0.125f;
        s_a[d]  = (emb_w[d] - ewm) * emb_ln_g[d];
        s_bb[d] = (emb_b[d] - ebm) * emb_ln_g[d];
    } else if (t == 80) {
        // wave1c: LN1 quadratic constants
        float ewm = 0.0f, ebm = 0.0f;
        #pragma unroll
        for (int d = 0; d < 8; ++d) { ewm += emb_w[d]; ebm += emb_b[d]; }
        ewm *= 0.125f; ebm *= 0.125f;
        float A = 0.0f, Bc = 0.0f, Cc = 0.0f;
        #pragma unroll
        for (int d = 0; d < 8; ++d) {
            const float dw = emb_w[d] - ewm, db = emb_b[d] - ebm;
            A = fmaf(dw, dw, A); Bc = fmaf(dw, db, Bc); Cc = fmaf(db, db, Cc);
        }
        s_sc[0] = A * 0.125f;
        s_sc[1] = 2.0f * Bc * 0.125f;
        s_sc[2] = Cc * 0.125f + 1e-5f;
    } else if (t >= 128 && t < 136) {
        // wave2a: c2[p]
        const int p = t - 128;
        float c = proj_b[p];
        #pragma unroll
        for (int o = 0; o < 8; ++o) {
            float ob2 = out_proj_b[o];
            #pragma unroll
            for (int e = 0; e < 8; ++e) ob2 = fmaf(out_proj_w[o*8+e], in_proj_b[16+e], ob2);
            c = fmaf(proj_w[p*8+o], ob2, c);
        }
        #pragma unroll
        for (int e = 0; e < 8; ++e) {
            float po = 0.0f;
            #pragma unroll
            for (int o = 0; o < 8; ++o) po = fmaf(proj_w[p*8+o], out_proj_w[o*8+e], po);
            #pragma unroll
            for (int d = 0; d < 8; ++d)
                c = fmaf(po * in_proj_w[(16+e)*8 + d], ln_b[d], c);
        }
        s_c2[p] = c;
    } else if (t == 136) {
        // wave2b: dot-product scalars (logit-path ones scaled by log2e)
        float qv[8]; float bkq = 0.0f;
        #pragma unroll
        for (int e = 0; e < 8; ++e) {
            float qe = in_proj_b[e];
            #pragma unroll
            for (int dd = 0; dd < 8; ++dd) qe = fmaf(in_proj_w[e*8+dd], var_query[dd], qe);
            qv[e] = qe;
            bkq = fmaf(in_proj_b[8+e], qe, bkq);
        }
        float ewm = 0.0f, ebm = 0.0f;
        #pragma unroll
        for (int d = 0; d < 8; ++d) { ewm += emb_w[d]; ebm += emb_b[d]; }
        ewm *= 0.125f; ebm *= 0.125f;
        float sa = 0, sb = 0, caa = 0, cbb = 0, cab = 0, ca = 0, cb = 0, sw = 0, ck = 0;
        #pragma unroll
        for (int d = 0; d < 8; ++d) {
            const float ad = (emb_w[d] - ewm) * emb_ln_g[d];
            const float bd = (emb_b[d] - ebm) * emb_ln_g[d];
            float wk = 0.0f;
            #pragma unroll
            for (int e = 0; e < 8; ++e) wk = fmaf(in_proj_w[(8+e)*8 + d], qv[e], wk);
            const float wl = ln_g[d] * wk * (INV_SQRT8 * LOG2E);
            sa += ad; sb += bd;
            caa = fmaf(ad, ad, caa); cbb = fmaf(bd, bd, cbb); cab = fmaf(ad, bd, cab);
            ca  = fmaf(ad, wl, ca);  cb  = fmaf(bd, wl, cb);
            sw += wl;
            ck  = fmaf(ln_b[d], wk, ck);
        }
        s_sc[3]  = sw;                                   // swlg' (log2e folded)
        s_sc[4]  = (ck * LOG2E + bkq * LOG2E) * INV_SQRT8;  // cK'
        s_sc[5]  = sa * 0.125f;
        s_sc[6]  = sb * 0.125f;
        s_sc[7]  = caa * 0.125f;
        s_sc[8]  = cbb * 0.125f;
        s_sc[9]  = cab * 0.25f;
        s_sc[10] = ca;
        s_sc[11] = cb;
    } else if (t >= 192 && t < 200) {
        // wave3: per-f table
        const int f = t - 192;
        const float ff = (float)f;
        float sy0, cy0, sy1, cy1;
        sincosf(ff, &sy0, &cy0);
        sincosf(0.01f * ff, &sy1, &cy1);
        float Bf[4];
        Bf[0] = emb_ln_b[4] + sy0; Bf[1] = emb_ln_b[5] + cy0;
        Bf[2] = emb_ln_b[6] + sy1; Bf[3] = emb_ln_b[7] + cy1;
        float ewm = 0.0f, ebm = 0.0f;
        #pragma unroll
        for (int d = 0; d < 8; ++d) { ewm += emb_w[d]; ebm += emb_b[d]; }
        ewm *= 0.125f; ebm *= 0.125f;
        float qv[8];
        #pragma unroll
        for (int e = 0; e < 8; ++e) {
            float qe = in_proj_b[e];
            #pragma unroll
            for (int dd = 0; dd < 8; ++dd) qe = fmaf(in_proj_w[e*8+dd], var_query[dd], qe);
            qv[e] = qe;
        }
        float bsum = 0, aB = 0, bB = 0, b2 = 0, bdot = 0;
        #pragma unroll
        for (int j = 0; j < 4; ++j) {
            const int d = 4 + j;
            const float ad = (emb_w[d] - ewm) * emb_ln_g[d];
            const float bd = (emb_b[d] - ebm) * emb_ln_g[d];
            float wk = 0.0f;
            #pragma unroll
            for (int e = 0; e < 8; ++e) wk = fmaf(in_proj_w[(8+e)*8 + d], qv[e], wk);
            const float wl = ln_g[d] * wk * (INV_SQRT8 * LOG2E);
            bsum += Bf[j];
            aB   = fmaf(ad, Bf[j], aB);
            bB   = fmaf(bd, Bf[j], bB);
            b2   = fmaf(Bf[j], Bf[j], b2);
            bdot = fmaf(wl, Bf[j], bdot);
            s_F[f][j] = Bf[j];
        }
        s_F[f][4] = bsum * 0.125f;
        s_F[f][5] = aB * 0.25f;
        s_F[f][6] = bB * 0.25f;
        s_F[f][7] = b2 * 0.125f;
        s_F[f][8] = bdot;            // log2e folded via wl
    }
    __syncthreads();

    const int w = pos & (W_DIM - 1);

    const float A    = s_sc[0], twoB = s_sc[1], Cc  = s_sc[2];
    const float swlg = s_sc[3], cK   = s_sc[4];
    const float sa8  = s_sc[5], sb8  = s_sc[6];
    const float caa8 = s_sc[7], cbb8 = s_sc[8], cab8 = s_sc[9];
    const float ca   = s_sc[10], cb  = s_sc[11];

    // per-thread w-dependent constants
    const float fw = (float)w;
    float s1, c1, sl, clo;
    sincosf(fw, &s1, &c1);
    sincosf(0.01f * fw, &sl, &clo);
    float pB[4];
    pB[0] = emb_ln_b[0] + s1;  pB[1] = emb_ln_b[1] + c1;
    pB[2] = emb_ln_b[2] + sl;  pB[3] = emb_ln_b[3] + clo;

    float pBsum = 0, apB = 0, bpB = 0, pB2 = 0, pBdot = 0;
    #pragma unroll
    for (int j = 0; j < 4; ++j) {
        pBsum += pB[j];
        apB   = fmaf(s_a[j],   pB[j], apB);
        bpB   = fmaf(s_bb[j],  pB[j], bpB);
        pB2   = fmaf(pB[j],    pB[j], pB2);
        pBdot = fmaf(s_wlg[j], pB[j], pBdot);
    }
    const float pBsum8  = pBsum * 0.125f;
    const float twoapB8 = apB * 0.25f;
    const float twobpB8 = bpB * 0.25f;
    const float pB28eps = fmaf(pB2, 0.125f, 1e-5f);

    const float xf[8] = {xa.x, xa.y, xa.z, xa.w, xb.x, xb.y, xb.z, xb.w};
    const int   mi[8] = {ma.x, ma.y, ma.z, ma.w, mb.x, mb.y, mb.z, mb.w};

    float S = 0, SC = 0, ctt = 0, crr = 0;
    float avB[4] = {0, 0, 0, 0};

    #pragma unroll
    for (int f = 0; f < 8; ++f) {
        const float F0 = s_F[f][0], F1 = s_F[f][1], F2 = s_F[f][2], F3 = s_F[f][3];
        const float F4 = s_F[f][4], F5 = s_F[f][5], F6 = s_F[f][6], F7 = s_F[f][7];
        const float F8 = s_F[f][8];
        const float xs = xf[f];
        const float r  = rsqrtf(fmaf(xs, fmaf(xs, A, twoB), Cc));
        const float tt = xs * r;
        const float mu = fmaf(tt, sa8, fmaf(r, sb8, pBsum8 + F4));
        const float s2v = fmaf(tt, fmaf(tt, caa8, fmaf(r, cab8, twoapB8 + F5)),
                               fmaf(r, fmaf(r, cbb8, twobpB8 + F6), pB28eps + F7));
        const float var = fmaf(-mu, mu, s2v);
        const float r2  = rsqrtf(var);
        const float dt  = fmaf(tt, ca, fmaf(r, cb, pBdot + F8));
        const float l2  = fmaf(r2, fmaf(-mu, swlg, dt), cK);   // log2-domain logit
        const float e   = exp2f(l2);
        const float pp  = mi[f] ? 0.0f : e;
        const float cf  = pp * r2;
        S += pp; SC += cf;
        ctt = fmaf(cf, tt, ctt);
        crr = fmaf(cf, r,  crr);
        avB[0] = fmaf(cf, F0, avB[0]);
        avB[1] = fmaf(cf, F1, avB[1]);
        avB[2] = fmaf(cf, F2, avB[2]);
        avB[3] = fmaf(cf, F3, avB[3]);
    }

    // smu reconstructed from accumulators (mu affine in tt, r, per-f const)
    const float sumAvB = (avB[0] + avB[1]) + (avB[2] + avB[3]);
    const float smu = fmaf(sa8, ctt, fmaf(sb8, crr, fmaf(pBsum8, SC, 0.125f * sumAvB)));

    const float invS = 1.0f / S;
    const float nism = -invS * smu;
    float q[8];
    #pragma unroll
    for (int j = 0; j < 4; ++j) {
        const float av = fmaf(ctt, s_a[j], fmaf(crr, s_bb[j], SC * pB[j]));
        q[j] = fmaf(invS, av, nism);
    }
    #pragma unroll
    for (int j = 0; j < 4; ++j) {
        const float av = fmaf(ctt, s_a[4+j], fmaf(crr, s_bb[4+j], avB[j]));
        q[4+j] = fmaf(invS, av, nism);
    }

    float o[8];
    #pragma unroll
    for (int p = 0; p < 8; ++p) {
        float dp = s_c2[p];
        #pragma unroll
        for (int d = 0; d < 8; ++d) dp = fmaf(s_M2[p*8+d], q[d], dp);
        o[p] = dp;
    }
    float4* ov4 = reinterpret_cast<float4*>(out);
    ov4[pos*2+0] = make_float4(o[0], o[1], o[2], o[3]);
    ov4[pos*2+1] = make_float4(o[4], o[5], o[6], o[7]);
}

extern "C" void kernel_launch(void* const* d_in, const int* in_sizes, int n_in,
                              void* d_out, int out_size, void* d_ws, size_t ws_size,
                              hipStream_t stream) {
    const float* x          = (const float*)d_in[0];
    const int*   m          = (const int*)d_in[1];
    const float* emb_w      = (const float*)d_in[2];
    const float* emb_b      = (const float*)d_in[3];
    const float* emb_ln_g   = (const float*)d_in[4];
    const float* emb_ln_b   = (const float*)d_in[5];
    const float* ln_g       = (const float*)d_in[6];
    const float* ln_b       = (const float*)d_in[7];
    const float* var_query  = (const float*)d_in[8];
    const float* in_proj_w  = (const float*)d_in[9];
    const float* in_proj_b  = (const float*)d_in[10];
    const float* out_proj_w = (const float*)d_in[11];
    const float* out_proj_b = (const float*)d_in[12];
    const float* proj_w     = (const float*)d_in[13];
    const float* proj_b     = (const float*)d_in[14];
    float* out = (float*)d_out;

    const int npos = in_sizes[0] / 8;                 // 262144
    const int grid = (npos + THREADS - 1) / THREADS;  // 1024
    misstsm_fused<<<grid, THREADS, 0, stream>>>(
        x, m, emb_w, emb_b, emb_ln_g, emb_ln_b, ln_g, ln_b, var_query,
        in_proj_w, in_proj_b, out_proj_w, out_proj_b, proj_w, proj_b,
        out, npos);
}